// Round 1
// 266.493 us; speedup vs baseline: 1.0281x; 1.0281x over previous
//
#include <hip/hip_runtime.h>
#include <hip/hip_bf16.h>

#define NHEADS 16
#define HDIM 64
#define SEQ 2048
#define BATCH 4
#define DMODEL 1024
#define MTOT (BATCH * SEQ)

typedef short v8s __attribute__((ext_vector_type(8)));
typedef short v4s __attribute__((ext_vector_type(4)));
typedef float v4f __attribute__((ext_vector_type(4)));
typedef float v16f __attribute__((ext_vector_type(16)));
typedef unsigned int v4u __attribute__((ext_vector_type(4)));
typedef unsigned short u16;
typedef unsigned int u32;

__device__ __forceinline__ u16 f2bf(float f) {
    union { float f; unsigned u; } v; v.f = f;
    unsigned r = v.u + 0x7FFFu + ((v.u >> 16) & 1u);
    return (u16)(r >> 16);
}

// async global->LDS, 16B/lane; LDS dest = wave-uniform base + lane*16.
__device__ __forceinline__ void g2l16(const u16* g, short* l) {
    __builtin_amdgcn_global_load_lds(
        (const __attribute__((address_space(1))) u32*)g,
        (__attribute__((address_space(3))) u32*)l, 16, 0, 0);
}

// v_cvt_pk_bf16_f32: pack two f32 -> one u32 of 2 bf16 (lo=a, hi=b)
__device__ __forceinline__ unsigned pk_bf16(float a, float b) {
    unsigned r;
    asm("v_cvt_pk_bf16_f32 %0, %1, %2" : "=v"(r) : "v"(a), "v"(b));
    return r;
}
// v_permlane32_swap_b32: x[32..63] <-> y[0..31]
__device__ __forceinline__ void pl32swap(unsigned& x, unsigned& y) {
    asm("v_permlane32_swap_b32 %0, %1" : "+v"(x), "+v"(y));
}
// Build one PV A-fragment (16 keys) from 8 lane-local P values.
// a0..a3 = group 2kc (keys 16kc+4hi+0..3), b0..b3 = group 2kc+1.
// After the two swaps, hi=0 lanes hold keys 16kc+0..7, hi=1 keys 16kc+8..15.
__device__ __forceinline__ v8s build_pa(float a0, float a1, float a2, float a3,
                                        float b0, float b1, float b2, float b3) {
    unsigned X  = pk_bf16(a0, a1);
    unsigned X2 = pk_bf16(a2, a3);
    unsigned Y  = pk_bf16(b0, b1);
    unsigned Y2 = pk_bf16(b2, b3);
    pl32swap(X, Y);    // X -> elems 0,1 ; Y -> elems 4,5
    pl32swap(X2, Y2);  // X2 -> elems 2,3; Y2 -> elems 6,7
    v4u w; w[0] = X; w[1] = X2; w[2] = Y; w[3] = Y2;
    return __builtin_bit_cast(v8s, w);
}

// ---------------------------------------------------------------------------
// x fp32 -> bf16, 8 elems/thread
// ---------------------------------------------------------------------------
__global__ __launch_bounds__(256)
void xcvt(const float* __restrict__ x, u16* __restrict__ xb)
{
    size_t i = ((size_t)blockIdx.x * 256 + threadIdx.x) * 8;
    v4f a = *(const v4f*)&x[i];
    v4f b = *(const v4f*)&x[i + 4];
    v8s p;
#pragma unroll
    for (int e = 0; e < 4; ++e) p[e] = (short)f2bf(a[e]);
#pragma unroll
    for (int e = 0; e < 4; ++e) p[4 + e] = (short)f2bf(b[e]);
    *(v8s*)&xb[i] = p;
}

// ---------------------------------------------------------------------------
// Weight transpose: src fp32 [k][n] -> dst bf16 [n][k].
// ---------------------------------------------------------------------------
__device__ __forceinline__ void transpose_body(
    const float* __restrict__ src, u16* __restrict__ dst, int k0, int n0)
{
    __shared__ __align__(8) short Ts[64 * 68];
    const int t = threadIdx.x;
    const int n4 = (t & 15) * 4, kl = t >> 4;
#pragma unroll
    for (int it = 0; it < 4; ++it) {
        int k = kl + 16 * it;
        v4f v = *(const v4f*)&src[(size_t)(k0 + k) * DMODEL + n0 + n4];
        v4s p;
#pragma unroll
        for (int e = 0; e < 4; ++e) p[e] = (short)f2bf(v[e]);
        *(v4s*)&Ts[k * 68 + n4] = p;
    }
    __syncthreads();
    const int nl = t >> 4, k4 = (t & 15) * 4;
#pragma unroll
    for (int it = 0; it < 4; ++it) {
        int n = nl + 16 * it;
        v4s o;
#pragma unroll
        for (int e = 0; e < 4; ++e) o[e] = Ts[(k4 + e) * 68 + n];
        *(v4s*)&dst[(size_t)(n0 + n) * DMODEL + k0 + k4] = o;
    }
}

__global__ __launch_bounds__(256)
void transpose_w(const float* __restrict__ src, u16* __restrict__ dst)
{
    transpose_body(src, dst, blockIdx.x * 64, blockIdx.y * 64);
}

__global__ __launch_bounds__(256)
void transpose_w4(const float* __restrict__ s0, const float* __restrict__ s1,
                  const float* __restrict__ s2, const float* __restrict__ s3,
                  u16* __restrict__ dst)
{
    const int z = blockIdx.z;
    const float* src = (z == 0) ? s0 : (z == 1) ? s1 : (z == 2) ? s2 : s3;
    transpose_body(src, dst + (size_t)z * DMODEL * DMODEL,
                   blockIdx.x * 64, blockIdx.y * 64);
}

// ---------------------------------------------------------------------------
// QKV epilogue. Q scale folds softmax 1/8 AND log2(e) (exp2 in attn).
// ---------------------------------------------------------------------------
#define QSCALE (0.125f * 1.44269504088896f)

__device__ __forceinline__ void qkv_epilogue(
    v4f (&acc)[4][4], int which, int n0, int m0, int wn, int wm,
    int l15, int quad, u16* Qb, u16* Kb, u16* Vt)
{
    if (which == 2) {
#pragma unroll
        for (int i = 0; i < 4; ++i)
#pragma unroll
            for (int j = 0; j < 4; ++j) {
                int col = n0 + wn + j * 16 + l15;
                int h = col >> 6, d = col & 63;
                int m = m0 + wm + i * 16 + quad * 4;
                int b = m >> 11, n = m & (SEQ - 1);
                v4s pv;
#pragma unroll
                for (int r = 0; r < 4; ++r) pv[r] = (short)f2bf(acc[i][j][r]);
                *(v4s*)&Vt[((size_t)(b * NHEADS + h) * HDIM + d) * SEQ + n] = pv;
            }
    } else {
        u16* Ob = (which == 0) ? Qb : Kb;
        const float scale = (which == 0) ? QSCALE : 1.0f;
#pragma unroll
        for (int i = 0; i < 4; ++i)
#pragma unroll
            for (int j = 0; j < 4; ++j) {
                int col = n0 + wn + j * 16 + l15;
                int h = col >> 6, d = col & 63;
#pragma unroll
                for (int r = 0; r < 4; ++r) {
                    int m = m0 + wm + i * 16 + quad * 4 + r;
                    int b = m >> 11, n = m & (SEQ - 1);
                    Ob[((size_t)(b * NHEADS + h) * SEQ + n) * HDIM + d] =
                        f2bf(acc[i][j][r] * scale);
                }
            }
    }
}

// ---------------------------------------------------------------------------
// qkv fast: both operands bf16 via global_load_lds. BK=64.
// ---------------------------------------------------------------------------
__global__ __launch_bounds__(256, 2)
void qkv_fast(const u16* __restrict__ xb, const u16* __restrict__ Wt,
              u16* __restrict__ Qb, u16* __restrict__ Kb, u16* __restrict__ Vt)
{
    __shared__ __align__(16) short As[128 * 64];
    __shared__ __align__(16) short Bs[128 * 64];

    const int which = blockIdx.z;
    const u16* W = Wt + (size_t)which * DMODEL * DMODEL;

    const int n0 = blockIdx.x * 128;
    const int m0 = blockIdx.y * 128;
    const int t = threadIdx.x;
    const int lane = t & 63;
    const int l15 = lane & 15;
    const int quad = lane >> 4;
    const int wave = t >> 6;
    const int wm = (wave >> 1) * 64;
    const int wn = (wave & 1) * 64;
    const int srow = t >> 3;
    const int sc8 = (t & 7) * 8;

    v4f acc[4][4];
#pragma unroll
    for (int i = 0; i < 4; ++i)
#pragma unroll
        for (int j = 0; j < 4; ++j) acc[i][j] = {0.f, 0.f, 0.f, 0.f};

    for (int k0 = 0; k0 < DMODEL; k0 += 64) {
        __syncthreads();
#pragma unroll
        for (int c = 0; c < 4; ++c) {
            g2l16(&xb[(size_t)(m0 + c * 32 + srow) * DMODEL + k0 + sc8],
                  &As[(c * 32 + srow) * 64 + sc8]);
            g2l16(&W[(size_t)(n0 + c * 32 + srow) * DMODEL + k0 + sc8],
                  &Bs[(c * 32 + srow) * 64 + sc8]);
        }
        __syncthreads();

#pragma unroll
        for (int kh = 0; kh < 2; ++kh) {
            v8s af[4], bf[4];
#pragma unroll
            for (int i = 0; i < 4; ++i)
                af[i] = *(const v8s*)
                    &As[(wm + i * 16 + l15) * 64 + kh * 32 + quad * 8];
#pragma unroll
            for (int j = 0; j < 4; ++j)
                bf[j] = *(const v8s*)
                    &Bs[(wn + j * 16 + l15) * 64 + kh * 32 + quad * 8];
#pragma unroll
            for (int i = 0; i < 4; ++i)
#pragma unroll
                for (int j = 0; j < 4; ++j)
                    acc[i][j] = __builtin_amdgcn_mfma_f32_16x16x32_bf16(
                        af[i], bf[j], acc[i][j], 0, 0, 0);
        }
    }
    qkv_epilogue(acc, which, n0, m0, wn, wm, l15, quad, Qb, Kb, Vt);
}

// ---------------------------------------------------------------------------
// qkv fallback: A = x fp32 converted at staging. BK=32.
// ---------------------------------------------------------------------------
__global__ __launch_bounds__(256, 2)
void qkv_slow(const float* __restrict__ x, const u16* __restrict__ Wt,
              u16* __restrict__ Qb, u16* __restrict__ Kb, u16* __restrict__ Vt)
{
    __shared__ __align__(16) short As[128 * 32];
    __shared__ __align__(16) short Bs[128 * 32];

    const int which = blockIdx.z;
    const u16* W = Wt + (size_t)which * DMODEL * DMODEL;

    const int n0 = blockIdx.x * 128;
    const int m0 = blockIdx.y * 128;
    const int t = threadIdx.x;
    const int lane = t & 63;
    const int l15 = lane & 15;
    const int quad = lane >> 4;
    const int wave = t >> 6;
    const int wm = (wave >> 1) * 64;
    const int wn = (wave & 1) * 64;
    const int srow = t >> 2;
    const int sc8 = (t & 3) * 8;

    v4f acc[4][4];
#pragma unroll
    for (int i = 0; i < 4; ++i)
#pragma unroll
        for (int j = 0; j < 4; ++j) acc[i][j] = {0.f, 0.f, 0.f, 0.f};

    for (int k0 = 0; k0 < DMODEL; k0 += 32) {
        __syncthreads();
        g2l16(&W[(size_t)(n0 + srow) * DMODEL + k0 + sc8], &Bs[srow * 32 + sc8]);
        g2l16(&W[(size_t)(n0 + 64 + srow) * DMODEL + k0 + sc8],
              &Bs[(64 + srow) * 32 + sc8]);
#pragma unroll
        for (int it = 0; it < 2; ++it) {
            int row = srow + 64 * it;
            const float* xp = &x[(size_t)(m0 + row) * DMODEL + k0 + sc8];
            v4f x0 = *(const v4f*)xp;
            v4f x1 = *(const v4f*)(xp + 4);
            v8s av;
#pragma unroll
            for (int e = 0; e < 4; ++e) av[e] = (short)f2bf(x0[e]);
#pragma unroll
            for (int e = 0; e < 4; ++e) av[4 + e] = (short)f2bf(x1[e]);
            *(v8s*)&As[row * 32 + sc8] = av;
        }
        __syncthreads();

        v8s af[4], bf[4];
#pragma unroll
        for (int i = 0; i < 4; ++i)
            af[i] = *(const v8s*)&As[(wm + i * 16 + l15) * 32 + quad * 8];
#pragma unroll
        for (int j = 0; j < 4; ++j)
            bf[j] = *(const v8s*)&Bs[(wn + j * 16 + l15) * 32 + quad * 8];
#pragma unroll
        for (int i = 0; i < 4; ++i)
#pragma unroll
            for (int j = 0; j < 4; ++j)
                acc[i][j] = __builtin_amdgcn_mfma_f32_16x16x32_bf16(
                    af[i], bf[j], acc[i][j], 0, 0, 0);
    }
    qkv_epilogue(acc, which, n0, m0, wn, wm, l15, quad, Qb, Kb, Vt);
}

// ---------------------------------------------------------------------------
// Stage 2: causal flash attention, 32x32x16 swapped-QK^T structure (m214/T12).
//   * 4 waves x 32 q-rows = 128-q blocks; q-tiles paired (p, 15-p) -> 512
//     uniform blocks x 34 k-iters of 64 keys.
//   * St = mfma(K, Q): each lane holds a full 32-key P slice for one q-row
//     (col=q=lane&31, row=key=(r&3)+8*(r>>2)+4*hi).
//   * P -> PV A-fragments fully in-register: v_cvt_pk_bf16_f32 +
//     v_permlane32_swap_b32 (no P LDS scatter, no lgkmcnt fence).
//   * Row-sum is lane-local; one shfl_xor(32) closes it.
// ---------------------------------------------------------------------------
#define KP 72   // K/V pitch: 144B rows

__global__ __launch_bounds__(256, 2)
void attn(const u16* __restrict__ Qb, const u16* __restrict__ Kb,
          const u16* __restrict__ Vt, u16* __restrict__ Cx)
{
    __shared__ __align__(16) short Ks[64 * KP];      // [key][d]
    __shared__ __align__(16) short Vs[64 * KP];      // [d][key]

    const int ell = blockIdx.x;            // 0..511
    const int xcd = ell & 7;
    const int rest = ell >> 3;             // 0..63
    const int p = rest & 7;                // pair index 0..7
    const int bh = ((rest >> 3) << 3) | xcd;

    const int t = threadIdx.x;
    const int lane = t & 63;
    const int l31 = lane & 31;
    const int hi = lane >> 5;
    const int wave = t >> 6;
    const int koff = hi * 8;

    const u16* Qh = Qb + (size_t)bh * SEQ * HDIM;
    const u16* Kh = Kb + (size_t)bh * SEQ * HDIM;
    const u16* Vh = Vt + (size_t)bh * HDIM * SEQ;

    const int skey = t >> 2;          // staging row (key for K, d for V)
    const int sd = (t & 3) * 16;
    const int b = bh >> 4, h = bh & 15;

#pragma unroll 1
    for (int phase = 0; phase < 2; ++phase) {
        const int qt = phase ? p : (15 - p);   // long tile first
        const int q0w = qt * 128 + wave * 32;
        const int kmax = 2 * qt + 1;           // last 64-key block index

        // Q as B-operand: Q[q0w+l31][dc*16 + hi*8 + e]
        v8s qf[4];
#pragma unroll
        for (int dc = 0; dc < 4; ++dc)
            qf[dc] = *(const v8s*)
                &Qh[(size_t)(q0w + l31) * HDIM + dc * 16 + koff];

        v16f o0, o1;
#pragma unroll
        for (int r = 0; r < 16; ++r) { o0[r] = 0.f; o1[r] = 0.f; }
        float ls = 0.f;

        // prefetch kb=0
        v8s pk0_, pk1_, pv0_, pv1_;
        {
            const u16* Kp = &Kh[(size_t)skey * HDIM + sd];
            pk0_ = *(const v8s*)Kp; pk1_ = *(const v8s*)(Kp + 8);
            const u16* Vp = &Vh[(size_t)skey * SEQ + sd];
            pv0_ = *(const v8s*)Vp; pv1_ = *(const v8s*)(Vp + 8);
        }

#pragma unroll 1
        for (int kb = 0; kb <= kmax; ++kb) {
            __syncthreads();
            *(v8s*)&Ks[skey * KP + sd] = pk0_;
            *(v8s*)&Ks[skey * KP + sd + 8] = pk1_;
            *(v8s*)&Vs[skey * KP + sd] = pv0_;
            *(v8s*)&Vs[skey * KP + sd + 8] = pv1_;
            __syncthreads();

            if (kb < kmax) {  // prefetch next, overlaps compute
                const u16* Kp = &Kh[(size_t)((kb + 1) * 64 + skey) * HDIM + sd];
                pk0_ = *(const v8s*)Kp; pk1_ = *(const v8s*)(Kp + 8);
                const u16* Vp = &Vh[(size_t)skey * SEQ + (kb + 1) * 64 + sd];
                pv0_ = *(const v8s*)Vp; pv1_ = *(const v8s*)(Vp + 8);
            }

            // wave-uniform guard: last block fully masked for waves 0,1
            if (kb * 64 <= q0w + 31) {
                const bool diag = (kb * 64 + 63 > q0w);
                const int qrow = q0w + l31;

                // QK^T swapped: St[key][q], two 32-key tiles
                v16f st0, st1;
#pragma unroll
                for (int r = 0; r < 16; ++r) { st0[r] = 0.f; st1[r] = 0.f; }
#pragma unroll
                for (int dc = 0; dc < 4; ++dc) {
                    v8s kf0 = *(const v8s*)&Ks[l31 * KP + dc * 16 + koff];
                    v8s kf1 = *(const v8s*)
                        &Ks[(32 + l31) * KP + dc * 16 + koff];
                    st0 = __builtin_amdgcn_mfma_f32_32x32x16_bf16(
                        kf0, qf[dc], st0, 0, 0, 0);
                    st1 = __builtin_amdgcn_mfma_f32_32x32x16_bf16(
                        kf1, qf[dc], st1, 0, 0, 0);
                }

                // softmax numerator (scores pre-scaled by 1/8*log2e in Q)
                v16f pe0, pe1;
                if (!diag) {
#pragma unroll
                    for (int r = 0; r < 16; ++r) {
                        pe0[r] = exp2f(st0[r]);
                        pe1[r] = exp2f(st1[r]);
                    }
                } else {
#pragma unroll
                    for (int r = 0; r < 16; ++r) {
                        int kl = kb * 64 + (r & 3) + 8 * (r >> 2) + 4 * hi;
                        pe0[r] = (kl > qrow) ? 0.f : exp2f(st0[r]);
                        pe1[r] = (kl + 32 > qrow) ? 0.f : exp2f(st1[r]);
                    }
                }
#pragma unroll
                for (int r = 0; r < 16; ++r) ls += pe0[r] + pe1[r];

                // in-register P -> A-fragments (T12)
                v8s pa0 = build_pa(pe0[0], pe0[1], pe0[2], pe0[3],
                                   pe0[4], pe0[5], pe0[6], pe0[7]);
                v8s pa1 = build_pa(pe0[8], pe0[9], pe0[10], pe0[11],
                                   pe0[12], pe0[13], pe0[14], pe0[15]);
                v8s pa2 = build_pa(pe1[0], pe1[1], pe1[2], pe1[3],
                                   pe1[4], pe1[5], pe1[6], pe1[7]);
                v8s pa3 = build_pa(pe1[8], pe1[9], pe1[10], pe1[11],
                                   pe1[12], pe1[13], pe1[14], pe1[15]);

                // PV: O[q][d], two d-tiles
#pragma unroll
                for (int kc = 0; kc < 4; ++kc) {
                    v8s pav = (kc == 0) ? pa0 : (kc == 1) ? pa1
                              : (kc == 2) ? pa2 : pa3;
                    v8s vf0 = *(const v8s*)&Vs[l31 * KP + kc * 16 + koff];
                    v8s vf1 = *(const v8s*)
                        &Vs[(32 + l31) * KP + kc * 16 + koff];
                    o0 = __builtin_amdgcn_mfma_f32_32x32x16_bf16(
                        pav, vf0, o0, 0, 0, 0);
                    o1 = __builtin_amdgcn_mfma_f32_32x32x16_bf16(
                        pav, vf1, o1, 0, 0, 0);
                }
            }
        }

        // close row-sums (lane + partner half), normalize, store
        ls += __shfl_xor(ls, 32, 64);
        float inv = 1.f / ls;
#pragma unroll
        for (int r = 0; r < 16; ++r) {
            int m = (r & 3) + 8 * (r >> 2) + 4 * hi;
            float im = __shfl(inv, m, 64);
            size_t idx = ((size_t)(b * SEQ + q0w + m)) * DMODEL
                         + h * HDIM + l31;
            Cx[idx] = f2bf(o0[r] * im);
            Cx[idx + 32] = f2bf(o1[r] * im);
        }
    }
}

// ---------------------------------------------------------------------------
// Stage 3: out = Cx @ W_o + b_o. Both operands async, BK=64.
// ---------------------------------------------------------------------------
__global__ __launch_bounds__(256, 2)
void out_gemm(const u16* __restrict__ Cx, const u16* __restrict__ WoT,
              const float* __restrict__ bo, float* __restrict__ Y)
{
    __shared__ __align__(16) short As[128 * 64];
    __shared__ __align__(16) short Bs[128 * 64];

    const int n0 = blockIdx.x * 128;
    const int m0 = blockIdx.y * 128;
    const int t = threadIdx.x;
    const int lane = t & 63;
    const int l15 = lane & 15;
    const int quad = lane >> 4;
    const int wave = t >> 6;
    const int wm = (wave >> 1) * 64;
    const int wn = (wave & 1) * 64;
    const int srow = t >> 3;
    const int sc8 = (t & 7) * 8;

    v4f acc[4][4];
#pragma unroll
    for (int i = 0; i < 4; ++i)
#pragma unroll
        for (int j = 0; j < 4; ++j) acc[i][j] = {0.f, 0.f, 0.f, 0.f};

    for (int k0 = 0; k0 < DMODEL; k0 += 64) {
        __syncthreads();
#pragma unroll
        for (int c = 0; c < 4; ++c) {
            g2l16(&Cx[(size_t)(m0 + c * 32 + srow) * DMODEL + k0 + sc8],
                  &As[(c * 32 + srow) * 64 + sc8]);
            g2l16(&WoT[(size_t)(n0 + c * 32 + srow) * DMODEL + k0 + sc8],
                  &Bs[(c * 32 + srow) * 64 + sc8]);
        }
        __syncthreads();

#pragma unroll
        for (int kh = 0; kh < 2; ++kh) {
            v8s af[4], bf[4];
#pragma unroll
            for (int i = 0; i < 4; ++i)
                af[i] = *(const v8s*)
                    &As[(wm + i * 16 + l15) * 64 + kh * 32 + quad * 8];
#pragma unroll
            for (int j = 0; j < 4; ++j)
                bf[j] = *(const v8s*)
                    &Bs[(wn + j * 16 + l15) * 64 + kh * 32 + quad * 8];
#pragma unroll
            for (int i = 0; i < 4; ++i)
#pragma unroll
                for (int j = 0; j < 4; ++j)
                    acc[i][j] = __builtin_amdgcn_mfma_f32_16x16x32_bf16(
                        af[i], bf[j], acc[i][j], 0, 0, 0);
        }
    }

#pragma unroll
    for (int i = 0; i < 4; ++i)
#pragma unroll
        for (int j = 0; j < 4; ++j) {
            int col = n0 + wn + j * 16 + l15;
            float bias = bo[col];
#pragma unroll
            for (int r = 0; r < 4; ++r) {
                int m = m0 + wm + i * 16 + quad * 4 + r;
                Y[(size_t)m * DMODEL + col] = acc[i][j][r] + bias;
            }
        }
}

// ---------------------------------------------------------------------------
extern "C" void kernel_launch(void* const* d_in, const int* in_sizes, int n_in,
                              void* d_out, int out_size, void* d_ws,
                              size_t ws_size, hipStream_t stream)
{
    const float* x  = (const float*)d_in[0];
    const float* Wq = (const float*)d_in[1];
    const float* Wk = (const float*)d_in[2];
    const float* Wv = (const float*)d_in[3];
    const float* Wo = (const float*)d_in[4];
    const float* bo = (const float*)d_in[5];
    float* Y = (float*)d_out;

    const size_t per = (size_t)BATCH * NHEADS * SEQ * HDIM;  // 8M elems
    const size_t wsz = (size_t)DMODEL * DMODEL;              // 1M elems
    u16* base = (u16*)d_ws;

    if (ws_size >= (size_t)72 * 1024 * 1024) {
        u16* xb  = base;
        u16* Cx  = base;                 // aliases xb (dead after qkv)
        u16* Wt4 = base + per;           // 4 transposed weights
        u16* Qb  = base + per + 4 * wsz;
        u16* Kb  = Qb + per;
        u16* Vt  = Kb + per;

        xcvt<<<MTOT * DMODEL / (256 * 8), 256, 0, stream>>>(x, xb);
        transpose_w4<<<dim3(16, 16, 4), 256, 0, stream>>>(Wq, Wk, Wv, Wo, Wt4);
        qkv_fast<<<dim3(DMODEL / 128, MTOT / 128, 3), 256, 0, stream>>>(
            xb, Wt4, Qb, Kb, Vt);
        attn<<<512, 256, 0, stream>>>(Qb, Kb, Vt, Cx);
        out_gemm<<<dim3(DMODEL / 128, MTOT / 128), 256, 0, stream>>>(
            Cx, Wt4 + 3 * wsz, bo, Y);
    } else {
        u16* Wt  = base;              // 3 weights [0,6MB)
        u16* Cx  = base;              // aliases Wt (dead after qkv)
        u16* Qb  = base + per;
        u16* WoT = base + per;        // aliases Qb after attn
        u16* Kb  = base + 2 * per;
        u16* Vt  = base + 3 * per;

        transpose_w<<<dim3(16, 16), 256, 0, stream>>>(Wq, Wt);
        transpose_w<<<dim3(16, 16), 256, 0, stream>>>(Wk, Wt + wsz);
        transpose_w<<<dim3(16, 16), 256, 0, stream>>>(Wv, Wt + 2 * wsz);
        qkv_slow<<<dim3(DMODEL / 128, MTOT / 128, 3), 256, 0, stream>>>(
            x, Wt, Qb, Kb, Vt);
        attn<<<512, 256, 0, stream>>>(Qb, Kb, Vt, Cx);
        transpose_w<<<dim3(16, 16), 256, 0, stream>>>(Wo, WoT);
        out_gemm<<<dim3(DMODEL / 128, MTOT / 128), 256, 0, stream>>>(
            Cx, WoT, bo, Y);
    }
}

// Round 2
// 258.004 us; speedup vs baseline: 1.0619x; 1.0329x over previous
//
#include <hip/hip_runtime.h>
#include <hip/hip_bf16.h>

#define NHEADS 16
#define HDIM 64
#define SEQ 2048
#define BATCH 4
#define DMODEL 1024
#define MTOT (BATCH * SEQ)

typedef short v8s __attribute__((ext_vector_type(8)));
typedef short v4s __attribute__((ext_vector_type(4)));
typedef float v4f __attribute__((ext_vector_type(4)));
typedef float v16f __attribute__((ext_vector_type(16)));
typedef unsigned int v4u __attribute__((ext_vector_type(4)));
typedef unsigned short u16;
typedef unsigned int u32;

__device__ __forceinline__ u16 f2bf(float f) {
    union { float f; unsigned u; } v; v.f = f;
    unsigned r = v.u + 0x7FFFu + ((v.u >> 16) & 1u);
    return (u16)(r >> 16);
}

// async global->LDS, 16B/lane; LDS dest = wave-uniform base + lane*16.
__device__ __forceinline__ void g2l16(const u16* g, short* l) {
    __builtin_amdgcn_global_load_lds(
        (const __attribute__((address_space(1))) u32*)g,
        (__attribute__((address_space(3))) u32*)l, 16, 0, 0);
}

// v_cvt_pk_bf16_f32: pack two f32 -> one u32 of 2 bf16 (lo=a, hi=b)
__device__ __forceinline__ unsigned pk_bf16(float a, float b) {
    unsigned r;
    asm("v_cvt_pk_bf16_f32 %0, %1, %2" : "=v"(r) : "v"(a), "v"(b));
    return r;
}
// v_permlane32_swap_b32: x[32..63] <-> y[0..31]
__device__ __forceinline__ void pl32swap(unsigned& x, unsigned& y) {
    asm("v_permlane32_swap_b32 %0, %1" : "+v"(x), "+v"(y));
}
// Build one PV A-fragment (16 keys) from 8 lane-local P values.
__device__ __forceinline__ v8s build_pa(float a0, float a1, float a2, float a3,
                                        float b0, float b1, float b2, float b3) {
    unsigned X  = pk_bf16(a0, a1);
    unsigned X2 = pk_bf16(a2, a3);
    unsigned Y  = pk_bf16(b0, b1);
    unsigned Y2 = pk_bf16(b2, b3);
    pl32swap(X, Y);
    pl32swap(X2, Y2);
    v4u w; w[0] = X; w[1] = X2; w[2] = Y; w[3] = Y2;
    return __builtin_bit_cast(v8s, w);
}

// ---------------------------------------------------------------------------
// x fp32 -> bf16, 8 elems/thread
// ---------------------------------------------------------------------------
__global__ __launch_bounds__(256)
void xcvt(const float* __restrict__ x, u16* __restrict__ xb)
{
    size_t i = ((size_t)blockIdx.x * 256 + threadIdx.x) * 8;
    v4f a = *(const v4f*)&x[i];
    v4f b = *(const v4f*)&x[i + 4];
    v8s p;
#pragma unroll
    for (int e = 0; e < 4; ++e) p[e] = (short)f2bf(a[e]);
#pragma unroll
    for (int e = 0; e < 4; ++e) p[4 + e] = (short)f2bf(b[e]);
    *(v8s*)&xb[i] = p;
}

// ---------------------------------------------------------------------------
// Weight transpose: src fp32 [k][n] -> dst bf16 [n][k].
// ---------------------------------------------------------------------------
__device__ __forceinline__ void transpose_body(
    const float* __restrict__ src, u16* __restrict__ dst, int k0, int n0)
{
    __shared__ __align__(8) short Ts[64 * 68];
    const int t = threadIdx.x;
    const int n4 = (t & 15) * 4, kl = t >> 4;
#pragma unroll
    for (int it = 0; it < 4; ++it) {
        int k = kl + 16 * it;
        v4f v = *(const v4f*)&src[(size_t)(k0 + k) * DMODEL + n0 + n4];
        v4s p;
#pragma unroll
        for (int e = 0; e < 4; ++e) p[e] = (short)f2bf(v[e]);
        *(v4s*)&Ts[k * 68 + n4] = p;
    }
    __syncthreads();
    const int nl = t >> 4, k4 = (t & 15) * 4;
#pragma unroll
    for (int it = 0; it < 4; ++it) {
        int n = nl + 16 * it;
        v4s o;
#pragma unroll
        for (int e = 0; e < 4; ++e) o[e] = Ts[(k4 + e) * 68 + n];
        *(v4s*)&dst[(size_t)(n0 + n) * DMODEL + k0 + k4] = o;
    }
}

__global__ __launch_bounds__(256)
void transpose_w(const float* __restrict__ src, u16* __restrict__ dst)
{
    transpose_body(src, dst, blockIdx.x * 64, blockIdx.y * 64);
}

__global__ __launch_bounds__(256)
void transpose_w4(const float* __restrict__ s0, const float* __restrict__ s1,
                  const float* __restrict__ s2, const float* __restrict__ s3,
                  u16* __restrict__ dst)
{
    const int z = blockIdx.z;
    const float* src = (z == 0) ? s0 : (z == 1) ? s1 : (z == 2) ? s2 : s3;
    transpose_body(src, dst + (size_t)z * DMODEL * DMODEL,
                   blockIdx.x * 64, blockIdx.y * 64);
}

// ---------------------------------------------------------------------------
// Q scale folds softmax 1/8 AND log2(e) (exp2 in attn).
// ---------------------------------------------------------------------------
#define QSCALE (0.125f * 1.44269504088896f)

// ---------------------------------------------------------------------------
// qkv256: fused C[8192][3072] = xb @ [Wq;Wk;Wv]^T, 256x256 8-phase schedule
// (T1+T2+T3+T4+T5). BK=64, 8 waves (2Mx4N), 128KiB dbuf LDS.
//  * T2: 16B-slot XOR swizzle (slot ^= row&7); gload_lds writes linearly so
//    the swizzle is applied to the GLOBAL source address + the ds_read addr
//    (both-sides rule #21).
//  * Staging calendar (buffer-deadness ledger):
//      A halves of tile s issue during tile s-1's P1/P2 (A last read at P3)
//      B halves of tile s issue during tile s-2's P3/P4 (B last read at P2)
//    => vmcnt(4) at each P4 guarantees tile t+1 fully resident; never 0
//    until the tail (t==14).
//  * Per phase: 16 MFMA quadrant; quadrant order (i0-3,j0-1),(i0-3,j2-3),
//    (i4-7,j2-3),(i4-7,j0-1) so B j0-1 frags stay live P1->P4.
// ---------------------------------------------------------------------------
#define BAR() __builtin_amdgcn_s_barrier()
#define LGKM0() do { asm volatile("s_waitcnt lgkmcnt(0)" ::: "memory"); \
                     __builtin_amdgcn_sched_barrier(0); } while (0)

#define STAGE_A(sbuf, stile, half, issue) \
    g2l16(&xb[(size_t)(m0 + (half) * 128 + (issue) * 64 + srr) * DMODEL + \
              (stile) * 64 + scol], \
          &As[sbuf][(half) * 8192 + (issue) * 4096 + t * 8])
#define STAGE_B(sbuf, stile, half, issue) \
    g2l16(&Wt[(size_t)(n0g + (half) * 128 + (issue) * 64 + srr) * DMODEL + \
              (stile) * 64 + scol], \
          &Bs[sbuf][(half) * 8192 + (issue) * 4096 + t * 8])

#define LDA_QUAD(bb, I0) \
    _Pragma("unroll") \
    for (int i = 0; i < 4; ++i) \
        _Pragma("unroll") \
        for (int kh = 0; kh < 2; ++kh) \
            af[i][kh] = *(const v8s*)&As[bb][ \
                (wm * 128 + ((I0) + i) * 16 + l15) * 64 + \
                (((kh * 4 + quad) ^ (l15 & 7)) << 3)];

#define LDB_PAIR(bb, J0) \
    _Pragma("unroll") \
    for (int j = 0; j < 2; ++j) \
        _Pragma("unroll") \
        for (int kh = 0; kh < 2; ++kh) \
            bf[(J0) + j][kh] = *(const v8s*)&Bs[bb][ \
                (wn * 64 + ((J0) + j) * 16 + l15) * 64 + \
                (((kh * 4 + quad) ^ (l15 & 7)) << 3)];

#define MFMA_QUAD(I0, J0) \
    _Pragma("unroll") \
    for (int i = 0; i < 4; ++i) \
        _Pragma("unroll") \
        for (int j = 0; j < 2; ++j) \
            _Pragma("unroll") \
            for (int kh = 0; kh < 2; ++kh) \
                acc[(I0) + i][(J0) + j] = \
                    __builtin_amdgcn_mfma_f32_16x16x32_bf16( \
                        af[i][kh], bf[(J0) + j][kh], \
                        acc[(I0) + i][(J0) + j], 0, 0, 0);

__global__ __launch_bounds__(512, 2)
void qkv256(const u16* __restrict__ xb, const u16* __restrict__ Wt,
            u16* __restrict__ Qb, u16* __restrict__ Kb, u16* __restrict__ Vt)
{
    __shared__ __align__(16) short As[2][256 * 64];
    __shared__ __align__(16) short Bs[2][256 * 64];

    // bijective XCD swizzle over 384 wgs (384 % 8 == 0)
    const int bid = blockIdx.x;
    const int swz = (bid & 7) * 48 + (bid >> 3);
    const int bx = swz % 12, by = swz / 12;
    const int n0g = bx * 256;          // global n in [0,3072)
    const int m0 = by * 256;

    const int t = threadIdx.x;
    const int lane = t & 63;
    const int l15 = lane & 15;
    const int quad = lane >> 4;
    const int wave = t >> 6;           // 0..7
    const int wm = wave >> 2;          // 0..1
    const int wn = wave & 3;           // 0..3

    // staging coords: 512 thr x 16B = one 64-row issue; source pre-swizzled
    const int srr = t >> 3;            // 0..63
    const int scol = (((t & 7) ^ (srr & 7)) << 3);

    v4f acc[8][4];
#pragma unroll
    for (int i = 0; i < 8; ++i)
#pragma unroll
        for (int j = 0; j < 4; ++j) acc[i][j] = {0.f, 0.f, 0.f, 0.f};

    // prologue: A(0), B(0), B(1); tile0 resident after vmcnt(4)
    STAGE_A(0, 0, 0, 0); STAGE_A(0, 0, 0, 1);
    STAGE_A(0, 0, 1, 0); STAGE_A(0, 0, 1, 1);
    STAGE_B(0, 0, 0, 0); STAGE_B(0, 0, 0, 1);
    STAGE_B(0, 0, 1, 0); STAGE_B(0, 0, 1, 1);
    STAGE_B(1, 1, 0, 0); STAGE_B(1, 1, 0, 1);
    STAGE_B(1, 1, 1, 0); STAGE_B(1, 1, 1, 1);
    asm volatile("s_waitcnt vmcnt(4)" ::: "memory");
    BAR();

#pragma unroll 1
    for (int tt = 0; tt < 16; ++tt) {
        const int cb = tt & 1;
        v8s af[4][2];
        v8s bf[4][2];

        // ---- P1: reads A i0-3 + B j0-1 (12 b128); stage A0(t+1)
        LDA_QUAD(cb, 0);
        LDB_PAIR(cb, 0);
        if (tt < 15) { STAGE_A(cb ^ 1, tt + 1, 0, 0);
                       STAGE_A(cb ^ 1, tt + 1, 0, 1); }
        BAR();
        LGKM0();
        __builtin_amdgcn_s_setprio(1);
        MFMA_QUAD(0, 0);
        __builtin_amdgcn_s_setprio(0);
        BAR();

        // ---- P2: reads B j2-3 (4); stage A1(t+1)
        LDB_PAIR(cb, 2);
        if (tt < 15) { STAGE_A(cb ^ 1, tt + 1, 1, 0);
                       STAGE_A(cb ^ 1, tt + 1, 1, 1); }
        BAR();
        LGKM0();
        __builtin_amdgcn_s_setprio(1);
        MFMA_QUAD(0, 2);
        __builtin_amdgcn_s_setprio(0);
        BAR();

        // ---- P3: reads A i4-7 (8); stage B0(t+2) (tile-t B reads done @P2)
        LDA_QUAD(cb, 4);
        if (tt < 14) { STAGE_B(cb, tt + 2, 0, 0);
                       STAGE_B(cb, tt + 2, 0, 1); }
        BAR();
        LGKM0();
        __builtin_amdgcn_s_setprio(1);
        MFMA_QUAD(4, 2);
        __builtin_amdgcn_s_setprio(0);
        BAR();

        // ---- P4: no reads; stage B1(t+2); counted vmcnt, never 0 in steady
        if (tt < 14) { STAGE_B(cb, tt + 2, 1, 0);
                       STAGE_B(cb, tt + 2, 1, 1); }
        BAR();
        __builtin_amdgcn_s_setprio(1);
        MFMA_QUAD(4, 0);
        __builtin_amdgcn_s_setprio(0);
        if (tt < 14)      asm volatile("s_waitcnt vmcnt(4)" ::: "memory");
        else if (tt == 14) asm volatile("s_waitcnt vmcnt(0)" ::: "memory");
        BAR();
    }

    // epilogue: route by output column (0..1023 Q, ..2047 K, ..3071 V)
#pragma unroll
    for (int i = 0; i < 8; ++i)
#pragma unroll
        for (int j = 0; j < 4; ++j) {
            int col = n0g + wn * 64 + j * 16 + l15;
            int which = col >> 10;
            int w = col & 1023;
            int h = w >> 6, d = w & 63;
            int mbase = m0 + wm * 128 + i * 16 + quad * 4;
            int bb = mbase >> 11, n = mbase & (SEQ - 1);
            if (which == 2) {
                v4s pv;
#pragma unroll
                for (int r = 0; r < 4; ++r) pv[r] = (short)f2bf(acc[i][j][r]);
                *(v4s*)&Vt[((size_t)(bb * NHEADS + h) * HDIM + d) * SEQ + n] = pv;
            } else {
                u16* Ob = which ? Kb : Qb;
                const float scale = which ? 1.0f : QSCALE;
#pragma unroll
                for (int r = 0; r < 4; ++r)
                    Ob[((size_t)(bb * NHEADS + h) * SEQ + n + r) * HDIM + d] =
                        f2bf(acc[i][j][r] * scale);
            }
        }
}

// ---------------------------------------------------------------------------
// qkv fallback: A = x fp32 converted at staging. BK=32. (small-ws path)
// ---------------------------------------------------------------------------
__device__ __forceinline__ void qkv_epilogue(
    v4f (&acc)[4][4], int which, int n0, int m0, int wn, int wm,
    int l15, int quad, u16* Qb, u16* Kb, u16* Vt)
{
    if (which == 2) {
#pragma unroll
        for (int i = 0; i < 4; ++i)
#pragma unroll
            for (int j = 0; j < 4; ++j) {
                int col = n0 + wn + j * 16 + l15;
                int h = col >> 6, d = col & 63;
                int m = m0 + wm + i * 16 + quad * 4;
                int b = m >> 11, n = m & (SEQ - 1);
                v4s pv;
#pragma unroll
                for (int r = 0; r < 4; ++r) pv[r] = (short)f2bf(acc[i][j][r]);
                *(v4s*)&Vt[((size_t)(b * NHEADS + h) * HDIM + d) * SEQ + n] = pv;
            }
    } else {
        u16* Ob = (which == 0) ? Qb : Kb;
        const float scale = (which == 0) ? QSCALE : 1.0f;
#pragma unroll
        for (int i = 0; i < 4; ++i)
#pragma unroll
            for (int j = 0; j < 4; ++j) {
                int col = n0 + wn + j * 16 + l15;
                int h = col >> 6, d = col & 63;
#pragma unroll
                for (int r = 0; r < 4; ++r) {
                    int m = m0 + wm + i * 16 + quad * 4 + r;
                    int b = m >> 11, n = m & (SEQ - 1);
                    Ob[((size_t)(b * NHEADS + h) * SEQ + n) * HDIM + d] =
                        f2bf(acc[i][j][r] * scale);
                }
            }
    }
}

__global__ __launch_bounds__(256, 2)
void qkv_slow(const float* __restrict__ x, const u16* __restrict__ Wt,
              u16* __restrict__ Qb, u16* __restrict__ Kb, u16* __restrict__ Vt)
{
    __shared__ __align__(16) short As[128 * 32];
    __shared__ __align__(16) short Bs[128 * 32];

    const int which = blockIdx.z;
    const u16* W = Wt + (size_t)which * DMODEL * DMODEL;

    const int n0 = blockIdx.x * 128;
    const int m0 = blockIdx.y * 128;
    const int t = threadIdx.x;
    const int lane = t & 63;
    const int l15 = lane & 15;
    const int quad = lane >> 4;
    const int wave = t >> 6;
    const int wm = (wave >> 1) * 64;
    const int wn = (wave & 1) * 64;
    const int srow = t >> 2;
    const int sc8 = (t & 3) * 8;

    v4f acc[4][4];
#pragma unroll
    for (int i = 0; i < 4; ++i)
#pragma unroll
        for (int j = 0; j < 4; ++j) acc[i][j] = {0.f, 0.f, 0.f, 0.f};

    for (int k0 = 0; k0 < DMODEL; k0 += 32) {
        __syncthreads();
        g2l16(&W[(size_t)(n0 + srow) * DMODEL + k0 + sc8], &Bs[srow * 32 + sc8]);
        g2l16(&W[(size_t)(n0 + 64 + srow) * DMODEL + k0 + sc8],
              &Bs[(64 + srow) * 32 + sc8]);
#pragma unroll
        for (int it = 0; it < 2; ++it) {
            int row = srow + 64 * it;
            const float* xp = &x[(size_t)(m0 + row) * DMODEL + k0 + sc8];
            v4f x0 = *(const v4f*)xp;
            v4f x1 = *(const v4f*)(xp + 4);
            v8s av;
#pragma unroll
            for (int e = 0; e < 4; ++e) av[e] = (short)f2bf(x0[e]);
#pragma unroll
            for (int e = 0; e < 4; ++e) av[4 + e] = (short)f2bf(x1[e]);
            *(v8s*)&As[row * 32 + sc8] = av;
        }
        __syncthreads();

        v8s af[4], bf[4];
#pragma unroll
        for (int i = 0; i < 4; ++i)
            af[i] = *(const v8s*)&As[(wm + i * 16 + l15) * 32 + quad * 8];
#pragma unroll
        for (int j = 0; j < 4; ++j)
            bf[j] = *(const v8s*)&Bs[(wn + j * 16 + l15) * 32 + quad * 8];
#pragma unroll
        for (int i = 0; i < 4; ++i)
#pragma unroll
            for (int j = 0; j < 4; ++j)
                acc[i][j] = __builtin_amdgcn_mfma_f32_16x16x32_bf16(
                    af[i], bf[j], acc[i][j], 0, 0, 0);
    }
    qkv_epilogue(acc, which, n0, m0, wn, wm, l15, quad, Qb, Kb, Vt);
}

// ---------------------------------------------------------------------------
// Stage 2: causal flash attention, 32x32x16 swapped-QK^T structure (m214/T12).
// ---------------------------------------------------------------------------
#define KP 72   // K/V pitch: 144B rows

__global__ __launch_bounds__(256, 2)
void attn(const u16* __restrict__ Qb, const u16* __restrict__ Kb,
          const u16* __restrict__ Vt, u16* __restrict__ Cx)
{
    __shared__ __align__(16) short Ks[64 * KP];      // [key][d]
    __shared__ __align__(16) short Vs[64 * KP];      // [d][key]

    const int ell = blockIdx.x;            // 0..511
    const int xcd = ell & 7;
    const int rest = ell >> 3;             // 0..63
    const int p = rest & 7;                // pair index 0..7
    const int bh = ((rest >> 3) << 3) | xcd;

    const int t = threadIdx.x;
    const int lane = t & 63;
    const int l31 = lane & 31;
    const int hi = lane >> 5;
    const int wave = t >> 6;
    const int koff = hi * 8;

    const u16* Qh = Qb + (size_t)bh * SEQ * HDIM;
    const u16* Kh = Kb + (size_t)bh * SEQ * HDIM;
    const u16* Vh = Vt + (size_t)bh * HDIM * SEQ;

    const int skey = t >> 2;          // staging row (key for K, d for V)
    const int sd = (t & 3) * 16;
    const int b = bh >> 4, h = bh & 15;

#pragma unroll 1
    for (int phase = 0; phase < 2; ++phase) {
        const int qt = phase ? p : (15 - p);   // long tile first
        const int q0w = qt * 128 + wave * 32;
        const int kmax = 2 * qt + 1;           // last 64-key block index

        v8s qf[4];
#pragma unroll
        for (int dc = 0; dc < 4; ++dc)
            qf[dc] = *(const v8s*)
                &Qh[(size_t)(q0w + l31) * HDIM + dc * 16 + koff];

        v16f o0, o1;
#pragma unroll
        for (int r = 0; r < 16; ++r) { o0[r] = 0.f; o1[r] = 0.f; }
        float ls = 0.f;

        v8s pk0_, pk1_, pv0_, pv1_;
        {
            const u16* Kp = &Kh[(size_t)skey * HDIM + sd];
            pk0_ = *(const v8s*)Kp; pk1_ = *(const v8s*)(Kp + 8);
            const u16* Vp = &Vh[(size_t)skey * SEQ + sd];
            pv0_ = *(const v8s*)Vp; pv1_ = *(const v8s*)(Vp + 8);
        }

#pragma unroll 1
        for (int kb = 0; kb <= kmax; ++kb) {
            __syncthreads();
            *(v8s*)&Ks[skey * KP + sd] = pk0_;
            *(v8s*)&Ks[skey * KP + sd + 8] = pk1_;
            *(v8s*)&Vs[skey * KP + sd] = pv0_;
            *(v8s*)&Vs[skey * KP + sd + 8] = pv1_;
            __syncthreads();

            if (kb < kmax) {
                const u16* Kp = &Kh[(size_t)((kb + 1) * 64 + skey) * HDIM + sd];
                pk0_ = *(const v8s*)Kp; pk1_ = *(const v8s*)(Kp + 8);
                const u16* Vp = &Vh[(size_t)skey * SEQ + (kb + 1) * 64 + sd];
                pv0_ = *(const v8s*)Vp; pv1_ = *(const v8s*)(Vp + 8);
            }

            if (kb * 64 <= q0w + 31) {
                const bool diag = (kb * 64 + 63 > q0w);
                const int qrow = q0w + l31;

                v16f st0, st1;
#pragma unroll
                for (int r = 0; r < 16; ++r) { st0[r] = 0.f; st1[r] = 0.f; }
#pragma unroll
                for (int dc = 0; dc < 4; ++dc) {
                    v8s kf0 = *(const v8s*)&Ks[l31 * KP + dc * 16 + koff];
                    v8s kf1 = *(const v8s*)
                        &Ks[(32 + l31) * KP + dc * 16 + koff];
                    st0 = __builtin_amdgcn_mfma_f32_32x32x16_bf16(
                        kf0, qf[dc], st0, 0, 0, 0);
                    st1 = __builtin_amdgcn_mfma_f32_32x32x16_bf16(
                        kf1, qf[dc], st1, 0, 0, 0);
                }

                v16f pe0, pe1;
                if (!diag) {
#pragma unroll
                    for (int r = 0; r < 16; ++r) {
                        pe0[r] = exp2f(st0[r]);
                        pe1[r] = exp2f(st1[r]);
                    }
                } else {
#pragma unroll
                    for (int r = 0; r < 16; ++r) {
                        int kl = kb * 64 + (r & 3) + 8 * (r >> 2) + 4 * hi;
                        pe0[r] = (kl > qrow) ? 0.f : exp2f(st0[r]);
                        pe1[r] = (kl + 32 > qrow) ? 0.f : exp2f(st1[r]);
                    }
                }
#pragma unroll
                for (int r = 0; r < 16; ++r) ls += pe0[r] + pe1[r];

                v8s pa0 = build_pa(pe0[0], pe0[1], pe0[2], pe0[3],
                                   pe0[4], pe0[5], pe0[6], pe0[7]);
                v8s pa1 = build_pa(pe0[8], pe0[9], pe0[10], pe0[11],
                                   pe0[12], pe0[13], pe0[14], pe0[15]);
                v8s pa2 = build_pa(pe1[0], pe1[1], pe1[2], pe1[3],
                                   pe1[4], pe1[5], pe1[6], pe1[7]);
                v8s pa3 = build_pa(pe1[8], pe1[9], pe1[10], pe1[11],
                                   pe1[12], pe1[13], pe1[14], pe1[15]);

#pragma unroll
                for (int kc = 0; kc < 4; ++kc) {
                    v8s pav = (kc == 0) ? pa0 : (kc == 1) ? pa1
                              : (kc == 2) ? pa2 : pa3;
                    v8s vf0 = *(const v8s*)&Vs[l31 * KP + kc * 16 + koff];
                    v8s vf1 = *(const v8s*)
                        &Vs[(32 + l31) * KP + kc * 16 + koff];
                    o0 = __builtin_amdgcn_mfma_f32_32x32x16_bf16(
                        pav, vf0, o0, 0, 0, 0);
                    o1 = __builtin_amdgcn_mfma_f32_32x32x16_bf16(
                        pav, vf1, o1, 0, 0, 0);
                }
            }
        }

        ls += __shfl_xor(ls, 32, 64);
        float inv = 1.f / ls;
#pragma unroll
        for (int r = 0; r < 16; ++r) {
            int m = (r & 3) + 8 * (r >> 2) + 4 * hi;
            float im = __shfl(inv, m, 64);
            size_t idx = ((size_t)(b * SEQ + q0w + m)) * DMODEL
                         + h * HDIM + l31;
            Cx[idx] = f2bf(o0[r] * im);
            Cx[idx + 32] = f2bf(o1[r] * im);
        }
    }
}

// ---------------------------------------------------------------------------
// Stage 3: out = Cx @ W_o + b_o. Both operands async, BK=64.
// ---------------------------------------------------------------------------
__global__ __launch_bounds__(256, 2)
void out_gemm(const u16* __restrict__ Cx, const u16* __restrict__ WoT,
              const float* __restrict__ bo, float* __restrict__ Y)
{
    __shared__ __align__(16) short As[128 * 64];
    __shared__ __align__(16) short Bs[128 * 64];

    const int n0 = blockIdx.x * 128;
    const int m0 = blockIdx.y * 128;
    const int t = threadIdx.x;
    const int lane = t & 63;
    const int l15 = lane & 15;
    const int quad = lane >> 4;
    const int wave = t >> 6;
    const int wm = (wave >> 1) * 64;
    const int wn = (wave & 1) * 64;
    const int srow = t >> 3;
    const int sc8 = (t & 7) * 8;

    v4f acc[4][4];
#pragma unroll
    for (int i = 0; i < 4; ++i)
#pragma unroll
        for (int j = 0; j < 4; ++j) acc[i][j] = {0.f, 0.f, 0.f, 0.f};

    for (int k0 = 0; k0 < DMODEL; k0 += 64) {
        __syncthreads();
#pragma unroll
        for (int c = 0; c < 4; ++c) {
            g2l16(&Cx[(size_t)(m0 + c * 32 + srow) * DMODEL + k0 + sc8],
                  &As[(c * 32 + srow) * 64 + sc8]);
            g2l16(&WoT[(size_t)(n0 + c * 32 + srow) * DMODEL + k0 + sc8],
                  &Bs[(c * 32 + srow) * 64 + sc8]);
        }
        __syncthreads();

#pragma unroll
        for (int kh = 0; kh < 2; ++kh) {
            v8s af[4], bf[4];
#pragma unroll
            for (int i = 0; i < 4; ++i)
                af[i] = *(const v8s*)
                    &As[(wm + i * 16 + l15) * 64 + kh * 32 + quad * 8];
#pragma unroll
            for (int j = 0; j < 4; ++j)
                bf[j] = *(const v8s*)
                    &Bs[(wn + j * 16 + l15) * 64 + kh * 32 + quad * 8];
#pragma unroll
            for (int i = 0; i < 4; ++i)
#pragma unroll
                for (int j = 0; j < 4; ++j)
                    acc[i][j] = __builtin_amdgcn_mfma_f32_16x16x32_bf16(
                        af[i], bf[j], acc[i][j], 0, 0, 0);
        }
    }

#pragma unroll
    for (int i = 0; i < 4; ++i)
#pragma unroll
        for (int j = 0; j < 4; ++j) {
            int col = n0 + wn + j * 16 + l15;
            float bias = bo[col];
#pragma unroll
            for (int r = 0; r < 4; ++r) {
                int m = m0 + wm + i * 16 + quad * 4 + r;
                Y[(size_t)m * DMODEL + col] = acc[i][j][r] + bias;
            }
        }
}

// ---------------------------------------------------------------------------
extern "C" void kernel_launch(void* const* d_in, const int* in_sizes, int n_in,
                              void* d_out, int out_size, void* d_ws,
                              size_t ws_size, hipStream_t stream)
{
    const float* x  = (const float*)d_in[0];
    const float* Wq = (const float*)d_in[1];
    const float* Wk = (const float*)d_in[2];
    const float* Wv = (const float*)d_in[3];
    const float* Wo = (const float*)d_in[4];
    const float* bo = (const float*)d_in[5];
    float* Y = (float*)d_out;

    const size_t per = (size_t)BATCH * NHEADS * SEQ * HDIM;  // 8M elems
    const size_t wsz = (size_t)DMODEL * DMODEL;              // 1M elems
    u16* base = (u16*)d_ws;

    if (ws_size >= (size_t)72 * 1024 * 1024) {
        u16* xb  = base;
        u16* Cx  = base;                 // aliases xb (dead after qkv)
        u16* Wt4 = base + per;           // 4 transposed weights
        u16* Qb  = base + per + 4 * wsz;
        u16* Kb  = Qb + per;
        u16* Vt  = Kb + per;

        xcvt<<<MTOT * DMODEL / (256 * 8), 256, 0, stream>>>(x, xb);
        transpose_w4<<<dim3(16, 16, 4), 256, 0, stream>>>(Wq, Wk, Wv, Wo, Wt4);
        qkv256<<<384, 512, 0, stream>>>(xb, Wt4, Qb, Kb, Vt);
        attn<<<512, 256, 0, stream>>>(Qb, Kb, Vt, Cx);
        out_gemm<<<dim3(DMODEL / 128, MTOT / 128), 256, 0, stream>>>(
            Cx, Wt4 + 3 * wsz, bo, Y);
    } else {
        u16* Wt  = base;              // 3 weights [0,6MB)
        u16* Cx  = base;              // aliases Wt (dead after qkv)
        u16* Qb  = base + per;
        u16* WoT = base + per;        // aliases Qb after attn
        u16* Kb  = base + 2 * per;
        u16* Vt  = base + 3 * per;

        transpose_w<<<dim3(16, 16), 256, 0, stream>>>(Wq, Wt);
        transpose_w<<<dim3(16, 16), 256, 0, stream>>>(Wk, Wt + wsz);
        transpose_w<<<dim3(16, 16), 256, 0, stream>>>(Wv, Wt + 2 * wsz);
        qkv_slow<<<dim3(DMODEL / 128, MTOT / 128, 3), 256, 0, stream>>>(
            x, Wt, Qb, Kb, Vt);
        attn<<<512, 256, 0, stream>>>(Qb, Kb, Vt, Cx);
        transpose_w<<<dim3(16, 16), 256, 0, stream>>>(Wo, WoT);
        out_gemm<<<dim3(DMODEL / 128, MTOT / 128), 256, 0, stream>>>(
            Cx, WoT, bo, Y);
    }
}